// Round 13
// baseline (71.457 us; speedup 1.0000x reference)
//
#include <hip/hip_runtime.h>
#include <stdint.h>

#define NT 4096
#define L2E 1.44269504f

typedef short s16x8 __attribute__((ext_vector_type(8)));
typedef short s16x4 __attribute__((ext_vector_type(4)));
typedef float f32x16 __attribute__((ext_vector_type(16)));
typedef float f32x4 __attribute__((ext_vector_type(4)));

__device__ __forceinline__ unsigned short f2bf(float f) {
  unsigned int u = __float_as_uint(f);
  u = u + 0x7FFFu + ((u >> 16) & 1u);   // RNE to bf16
  return (unsigned short)(u >> 16);
}

// pack 16 f32 p-values into two P A-fragments (verified R2..R6 map)
__device__ __forceinline__ void pack_pa(const float* p, s16x8* pa) {
  unsigned w8[8];
#pragma unroll
  for (int m = 0; m < 8; ++m)
    asm("v_cvt_pk_bf16_f32 %0, %1, %2" : "=v"(w8[m]) : "v"(p[2 * m]), "v"(p[2 * m + 1]));
  unsigned a0 = w8[0], b0 = w8[2]; asm("v_permlane32_swap_b32 %0, %1" : "+v"(a0), "+v"(b0));
  unsigned a1 = w8[1], b1 = w8[3]; asm("v_permlane32_swap_b32 %0, %1" : "+v"(a1), "+v"(b1));
  unsigned c0 = w8[4], d0 = w8[6]; asm("v_permlane32_swap_b32 %0, %1" : "+v"(c0), "+v"(d0));
  unsigned c1 = w8[5], d1 = w8[7]; asm("v_permlane32_swap_b32 %0, %1" : "+v"(c1), "+v"(d1));
  union PW { unsigned u[4]; s16x8 v; } q0, q1;
  q0.u[0] = a0; q0.u[1] = a1; q0.u[2] = b0; q0.u[3] = b1;
  q1.u[0] = c0; q1.u[1] = c1; q1.u[2] = d0; q1.u[3] = d1;
  pa[0] = q0.v; pa[1] = q1.v;
}

// ============================================================================
// Projection (verified): [wv(128); wq(16); wk(16)*log2e] @ x.
// grid 256 = b(4) x ntile64. qws/kws bf16 [b][n][16]; vfrag bf16 [b][jt][c][hi][8j]
// ============================================================================
__global__ __launch_bounds__(512, 2) void proj_kern(
    const float* __restrict__ x,
    const float* __restrict__ wq, const float* __restrict__ bq,
    const float* __restrict__ wk, const float* __restrict__ bk,
    const float* __restrict__ wv, const float* __restrict__ bv,
    short* __restrict__ qws, short* __restrict__ kws, short* __restrict__ vfrag) {
  __shared__ __align__(16) unsigned short w_s[160 * 128];
  __shared__ __align__(16) unsigned short xv_s[128 * 72];

  int t = threadIdx.x;
  int blk = blockIdx.x;
  int b = blk >> 6;
  int n0 = (blk & 63) * 64;

  for (int i4 = t; i4 < 5120; i4 += 512) {
    int row = i4 >> 5, ka = (i4 & 31) * 4;
    f32x4 v;
    float sc = 1.0f;
    if (row < 128)      v = *(const f32x4*)(wv + row * 128 + ka);
    else if (row < 144) v = *(const f32x4*)(wq + (row - 128) * 128 + ka);
    else              { v = *(const f32x4*)(wk + (row - 144) * 128 + ka); sc = L2E; }
    s16x4 o;
#pragma unroll
    for (int j = 0; j < 4; ++j) o[j] = (short)f2bf(v[j] * sc);
    unsigned byt = ((unsigned)(ka * 2)) ^ (((unsigned)row & 7u) << 4);
    *(s16x4*)((char*)w_s + row * 256 + byt) = o;
  }
  {
    int cL = t >> 4, nn4 = (t & 15) * 4;
    for (int cc = 0; cc < 128; cc += 32) {
      int c = cc + cL;
      f32x4 v = *(const f32x4*)(x + ((size_t)b * 128 + c) * NT + n0 + nn4);
      s16x4 o;
#pragma unroll
      for (int j = 0; j < 4; ++j) o[j] = (short)f2bf(v[j]);
      *(s16x4*)(xv_s + c * 64 + nn4) = o;
    }
  }
  __syncthreads();

  int w = t >> 6, lane = t & 63, lc = lane & 31, hi = lane >> 5;
  int rblk = w >> 1, nc = w & 1;
  int nn = nc * 32 + lc;

  f32x16 zf = {0.f,0.f,0.f,0.f,0.f,0.f,0.f,0.f,0.f,0.f,0.f,0.f,0.f,0.f,0.f,0.f};
  f32x16 acc = zf, acc2 = zf;

#pragma unroll
  for (int kk = 0; kk < 8; ++kk) {
    int kb0 = kk * 16 + hi * 8;
    s16x8 xf;
#pragma unroll
    for (int e = 0; e < 8; ++e) xf[e] = (short)xv_s[(kb0 + e) * 64 + nn];
    unsigned byt = ((unsigned)(kk * 32 + hi * 16)) ^ (((unsigned)lc & 7u) << 4);
    s16x8 af = *(const s16x8*)((const char*)w_s + (rblk * 32 + lc) * 256 + byt);
    acc = __builtin_amdgcn_mfma_f32_32x32x16_bf16(af, xf, acc, 0, 0, 0);
    if (rblk == 3) {
      s16x8 af2 = *(const s16x8*)((const char*)w_s + (128 + lc) * 256 + byt);
      acc2 = __builtin_amdgcn_mfma_f32_32x32x16_bf16(af2, xf, acc2, 0, 0, 0);
    }
  }

  if (rblk == 3) {
    size_t nidx = ((size_t)b * NT + n0 + nn) * 16;
    s16x4 q0, q1, k0, k1;
#pragma unroll
    for (int j = 0; j < 4; ++j) {
      q0[j] = (short)f2bf(acc2[j]      + bq[j + 4 * hi]);
      q1[j] = (short)f2bf(acc2[j + 4]  + bq[j + 8 + 4 * hi]);
      k0[j] = (short)f2bf(acc2[j + 8]  + bk[j + 4 * hi] * L2E);
      k1[j] = (short)f2bf(acc2[j + 12] + bk[j + 8 + 4 * hi] * L2E);
    }
    *(s16x4*)(qws + nidx + 4 * hi)     = q0;
    *(s16x4*)(qws + nidx + 8 + 4 * hi) = q1;
    *(s16x4*)(kws + nidx + 4 * hi)     = k0;
    *(s16x4*)(kws + nidx + 8 + 4 * hi) = k1;
  }

  __syncthreads();
#pragma unroll
  for (int r = 0; r < 16; ++r) {
    int c = rblk * 32 + (r & 3) + 8 * (r >> 2) + 4 * hi;
    xv_s[c * 72 + nn] = f2bf(acc[r] + bv[c]);
  }
  __syncthreads();
#pragma unroll
  for (int p = 0; p < 2; ++p) {
    int gid = t + p * 512;
    int c = gid & 127, ng = gid >> 7;
    s16x8 v = *(const s16x8*)(xv_s + c * 72 + ng * 8);
    size_t idx = (((size_t)b * 256 + (n0 >> 4) + (ng >> 1)) * 128 + c) * 16 + (ng & 1) * 8;
    *(s16x8*)(vfrag + idx) = v;
  }
}

// ============================================================================
// Flash attention: grid 512 = b(4) x it(128 tiles of 32 i). 512 thr = 8 waves
// = 4 private j-streams (1024 j, 32 steps) x 2 c-halves (64 c each).
// Slim state (~112 regs/lane) + __launch_bounds__(512,4) -> 4 waves/SIMD,
// 2 blocks/CU, 16 waves/CU. Softmax duplicated across the c-pair. No LDS /
// barriers in main loop. Fixed-base softmax p = 2^e. acc = mfma(P_A,V_B).
// ============================================================================
__global__ __launch_bounds__(512, 4) void attn_mfma(
    const short* __restrict__ qws, const short* __restrict__ kws, const short* __restrict__ vfrag,
    const float* __restrict__ x, const float* __restrict__ gp, float* __restrict__ out) {
  __shared__ __align__(16) unsigned char lds[18048];
  // rg0 @0 (8704B f32[32][68]), rg1 @8704; lsc @17408 (4*32 f32); linv @17920 (32 f32)

  int g = blockIdx.x;
  int gg = (g & 7) * 64 + (g >> 3);   // XCD swizzle: batch pinned to XCD pair
  int b = gg >> 7;
  int it = gg & 127;
  int t = threadIdx.x;
  int w = t >> 6, lane = t & 63, lc = lane & 31, hi = lane >> 5;
  int s = w >> 1, ch = w & 1;         // j-stream, c-half
  int jt0 = s * 1024;

  const short* qb = qws + (size_t)b * NT * 16;
  const short* kb = kws + (size_t)b * NT * 16;
  const short* vfb = vfrag + (size_t)b * 256 * 128 * 16;

  s16x8 qf = *(const s16x8*)(qb + (size_t)(it * 32 + lc) * 16 + hi * 8);

  f32x16 zf = {0.f,0.f,0.f,0.f,0.f,0.f,0.f,0.f,0.f,0.f,0.f,0.f,0.f,0.f,0.f,0.f};
  f32x16 acc[2];
  acc[0] = zf; acc[1] = zf;
  float lsum = 0.f;

  for (int st = 0; st < 32; ++st) {
    int j0 = jt0 + st * 32;
    int jtb = j0 >> 4;
    s16x8 kf = *(const s16x8*)(kb + (size_t)(j0 + lc) * 16 + hi * 8);
    // V fragments for this wave's c-half (4 x 8B/lane, coalesced, L2-hit)
    s16x8 vc[2][2];
#pragma unroll
    for (int sl = 0; sl < 2; ++sl)
#pragma unroll
      for (int cbi = 0; cbi < 2; ++cbi)
        vc[sl][cbi] = *(const s16x8*)(vfb + ((size_t)(jtb + sl) * 128 + (ch * 2 + cbi) * 32 + lc) * 16 + hi * 8);

    // QK^T swapped, exp2 domain: e[r] = E[j0+crow(r,hi)][i0+lc]
    f32x16 e = __builtin_amdgcn_mfma_f32_32x32x16_bf16(kf, qf, zf, 0, 0, 0);
#pragma unroll
    for (int r = 0; r < 16; ++r) e[r] = __builtin_amdgcn_exp2f(e[r]);
    float a0 = 0.f;
#pragma unroll
    for (int r = 0; r < 16; ++r) a0 += e[r];
    lsum += a0;

    s16x8 pa[2];
    pack_pa((const float*)&e, pa);

    __builtin_amdgcn_s_setprio(1);
#pragma unroll
    for (int sl = 0; sl < 2; ++sl)
#pragma unroll
      for (int cbi = 0; cbi < 2; ++cbi)
        acc[cbi] = __builtin_amdgcn_mfma_f32_32x32x16_bf16(pa[sl], vc[sl][cbi], acc[cbi], 0, 0, 0);
    __builtin_amdgcn_s_setprio(0);
  }

  // ---- merge 4 streams per c-half: s==0 stores, others LDS atomicAdd ----
  float* rg_my = (float*)(lds + (ch ? 8704 : 0));
  float* lsc   = (float*)(lds + 17408);
  float* linv  = (float*)(lds + 17920);

  float lf = lsum + __shfl_xor(lsum, 32);   // lanes: full row sum for i = i0+lc
  if (ch == 0 && hi == 0) lsc[s * 32 + lc] = lf;

  if (s == 0) {
#pragma unroll
    for (int cbi = 0; cbi < 2; ++cbi)
#pragma unroll
      for (int r = 0; r < 16; ++r) {
        int i = (r & 3) + 8 * (r >> 2) + 4 * hi;
        rg_my[i * 68 + cbi * 32 + lc] = acc[cbi][r];
      }
  }
  __syncthreads();                                   // B1
  if (t < 32) {
    float L = lsc[t] + lsc[32 + t] + lsc[64 + t] + lsc[96 + t];
    linv[t] = 1.0f / L;
  }
  if (s != 0) {
#pragma unroll
    for (int cbi = 0; cbi < 2; ++cbi)
#pragma unroll
      for (int r = 0; r < 16; ++r) {
        int i = (r & 3) + 8 * (r >> 2) + 4 * hi;
        atomicAdd(&rg_my[i * 68 + cbi * 32 + lc], acc[cbi][r]);
      }
  }
  __syncthreads();                                   // B2

  // ---- epilogue: o = gamma * D/L + x ----
  float gam = gp[0];
  int cc = t >> 2, iq = t & 3;
  const float* rgc = (const float*)(lds + ((cc & 64) ? 8704 : 0));
  int cp = cc & 63;
  size_t base = ((size_t)b * 128 + cc) * NT + it * 32 + iq * 8;
#pragma unroll
  for (int q2 = 0; q2 < 2; ++q2) {
    f32x4 xv = *(const f32x4*)(x + base + q2 * 4);
    f32x4 ov;
#pragma unroll
    for (int j = 0; j < 4; ++j) {
      int i = iq * 8 + q2 * 4 + j;
      ov[j] = gam * rgc[i * 68 + cp] * linv[i] + xv[j];
    }
    *(f32x4*)(out + base + q2 * 4) = ov;
  }
}

extern "C" void kernel_launch(void* const* d_in, const int* in_sizes, int n_in,
                              void* d_out, int out_size, void* d_ws, size_t ws_size,
                              hipStream_t stream) {
  const float* x     = (const float*)d_in[0];
  const float* wq    = (const float*)d_in[1];
  const float* bq    = (const float*)d_in[2];
  const float* wk    = (const float*)d_in[3];
  const float* bk    = (const float*)d_in[4];
  const float* wv    = (const float*)d_in[5];
  const float* bv    = (const float*)d_in[6];
  const float* gamma = (const float*)d_in[7];
  float* out = (float*)d_out;

  short* qws   = (short*)d_ws;                       // 512 KB
  short* kws   = qws + (size_t)4 * NT * 16;          // 512 KB
  short* vfrag = kws + (size_t)4 * NT * 16;          // 4 MB

  proj_kern<<<256, 512, 0, stream>>>(x, wq, bq, wk, bk, wv, bv, qws, kws, vfrag);
  attn_mfma<<<512, 512, 0, stream>>>(qws, kws, vfrag, x, gamma, out);
}

// Round 14
// 43.681 us; speedup vs baseline: 1.6359x; 1.6359x over previous
//
#include <hip/hip_runtime.h>
#include <stdint.h>

#define NT 4096
#define L2E 1.44269504f

typedef short s16x8 __attribute__((ext_vector_type(8)));
typedef short s16x4 __attribute__((ext_vector_type(4)));
typedef float f32x16 __attribute__((ext_vector_type(16)));
typedef float f32x4 __attribute__((ext_vector_type(4)));

__device__ __forceinline__ unsigned short f2bf(float f) {
  unsigned int u = __float_as_uint(f);
  u = u + 0x7FFFu + ((u >> 16) & 1u);   // RNE to bf16
  return (unsigned short)(u >> 16);
}

// pack 16 f32 p-values into two P A-fragments (verified R2..R6 map)
__device__ __forceinline__ void pack_pa(const float* p, s16x8* pa) {
  unsigned w8[8];
#pragma unroll
  for (int m = 0; m < 8; ++m)
    asm("v_cvt_pk_bf16_f32 %0, %1, %2" : "=v"(w8[m]) : "v"(p[2 * m]), "v"(p[2 * m + 1]));
  unsigned a0 = w8[0], b0 = w8[2]; asm("v_permlane32_swap_b32 %0, %1" : "+v"(a0), "+v"(b0));
  unsigned a1 = w8[1], b1 = w8[3]; asm("v_permlane32_swap_b32 %0, %1" : "+v"(a1), "+v"(b1));
  unsigned c0 = w8[4], d0 = w8[6]; asm("v_permlane32_swap_b32 %0, %1" : "+v"(c0), "+v"(d0));
  unsigned c1 = w8[5], d1 = w8[7]; asm("v_permlane32_swap_b32 %0, %1" : "+v"(c1), "+v"(d1));
  union PW { unsigned u[4]; s16x8 v; } q0, q1;
  q0.u[0] = a0; q0.u[1] = a1; q0.u[2] = b0; q0.u[3] = b1;
  q1.u[0] = c0; q1.u[1] = c1; q1.u[2] = d0; q1.u[3] = d1;
  pa[0] = q0.v; pa[1] = q1.v;
}

// merge helpers; scr layout f32 [64 i][132 c]; i = isub*32 + crow(r,hi), c = cb*32+lc
__device__ __forceinline__ void merge_write(float* scr, const f32x16 (&acc)[2][4],
                                            int lc, int hi) {
#pragma unroll
  for (int isub = 0; isub < 2; ++isub)
#pragma unroll
    for (int cb = 0; cb < 4; ++cb)
#pragma unroll
      for (int r = 0; r < 16; ++r) {
        int i = isub * 32 + (r & 3) + 8 * (r >> 2) + 4 * hi;
        scr[i * 132 + cb * 32 + lc] = acc[isub][cb][r];
      }
}
__device__ __forceinline__ void merge_add(const float* scr, f32x16 (&acc)[2][4],
                                          int lc, int hi) {
#pragma unroll
  for (int isub = 0; isub < 2; ++isub)
#pragma unroll
    for (int cb = 0; cb < 4; ++cb)
#pragma unroll
      for (int r = 0; r < 16; ++r) {
        int i = isub * 32 + (r & 3) + 8 * (r >> 2) + 4 * hi;
        acc[isub][cb][r] += scr[i * 132 + cb * 32 + lc];
      }
}

// ============================================================================
// Projection (verified): [wv(128); wq(16); wk(16)*log2e] @ x.
// grid 256 = b(4) x ntile64. qws/kws bf16 [b][n][16]; vfrag bf16 [b][jt][c][hi][8j]
// ============================================================================
__global__ __launch_bounds__(512, 2) void proj_kern(
    const float* __restrict__ x,
    const float* __restrict__ wq, const float* __restrict__ bq,
    const float* __restrict__ wk, const float* __restrict__ bk,
    const float* __restrict__ wv, const float* __restrict__ bv,
    short* __restrict__ qws, short* __restrict__ kws, short* __restrict__ vfrag) {
  __shared__ __align__(16) unsigned short w_s[160 * 128];
  __shared__ __align__(16) unsigned short xv_s[128 * 72];

  int t = threadIdx.x;
  int blk = blockIdx.x;
  int b = blk >> 6;
  int n0 = (blk & 63) * 64;

  for (int i4 = t; i4 < 5120; i4 += 512) {
    int row = i4 >> 5, ka = (i4 & 31) * 4;
    f32x4 v;
    float sc = 1.0f;
    if (row < 128)      v = *(const f32x4*)(wv + row * 128 + ka);
    else if (row < 144) v = *(const f32x4*)(wq + (row - 128) * 128 + ka);
    else              { v = *(const f32x4*)(wk + (row - 144) * 128 + ka); sc = L2E; }
    s16x4 o;
#pragma unroll
    for (int j = 0; j < 4; ++j) o[j] = (short)f2bf(v[j] * sc);
    unsigned byt = ((unsigned)(ka * 2)) ^ (((unsigned)row & 7u) << 4);
    *(s16x4*)((char*)w_s + row * 256 + byt) = o;
  }
  {
    int cL = t >> 4, nn4 = (t & 15) * 4;
    for (int cc = 0; cc < 128; cc += 32) {
      int c = cc + cL;
      f32x4 v = *(const f32x4*)(x + ((size_t)b * 128 + c) * NT + n0 + nn4);
      s16x4 o;
#pragma unroll
      for (int j = 0; j < 4; ++j) o[j] = (short)f2bf(v[j]);
      *(s16x4*)(xv_s + c * 64 + nn4) = o;
    }
  }
  __syncthreads();

  int w = t >> 6, lane = t & 63, lc = lane & 31, hi = lane >> 5;
  int rblk = w >> 1, nc = w & 1;
  int nn = nc * 32 + lc;

  f32x16 zf = {0.f,0.f,0.f,0.f,0.f,0.f,0.f,0.f,0.f,0.f,0.f,0.f,0.f,0.f,0.f,0.f};
  f32x16 acc = zf, acc2 = zf;

#pragma unroll
  for (int kk = 0; kk < 8; ++kk) {
    int kb0 = kk * 16 + hi * 8;
    s16x8 xf;
#pragma unroll
    for (int e = 0; e < 8; ++e) xf[e] = (short)xv_s[(kb0 + e) * 64 + nn];
    unsigned byt = ((unsigned)(kk * 32 + hi * 16)) ^ (((unsigned)lc & 7u) << 4);
    s16x8 af = *(const s16x8*)((const char*)w_s + (rblk * 32 + lc) * 256 + byt);
    acc = __builtin_amdgcn_mfma_f32_32x32x16_bf16(af, xf, acc, 0, 0, 0);
    if (rblk == 3) {
      s16x8 af2 = *(const s16x8*)((const char*)w_s + (128 + lc) * 256 + byt);
      acc2 = __builtin_amdgcn_mfma_f32_32x32x16_bf16(af2, xf, acc2, 0, 0, 0);
    }
  }

  if (rblk == 3) {
    size_t nidx = ((size_t)b * NT + n0 + nn) * 16;
    s16x4 q0, q1, k0, k1;
#pragma unroll
    for (int j = 0; j < 4; ++j) {
      q0[j] = (short)f2bf(acc2[j]      + bq[j + 4 * hi]);
      q1[j] = (short)f2bf(acc2[j + 4]  + bq[j + 8 + 4 * hi]);
      k0[j] = (short)f2bf(acc2[j + 8]  + bk[j + 4 * hi] * L2E);
      k1[j] = (short)f2bf(acc2[j + 12] + bk[j + 8 + 4 * hi] * L2E);
    }
    *(s16x4*)(qws + nidx + 4 * hi)     = q0;
    *(s16x4*)(qws + nidx + 8 + 4 * hi) = q1;
    *(s16x4*)(kws + nidx + 4 * hi)     = k0;
    *(s16x4*)(kws + nidx + 8 + 4 * hi) = k1;
  }

  __syncthreads();
#pragma unroll
  for (int r = 0; r < 16; ++r) {
    int c = rblk * 32 + (r & 3) + 8 * (r >> 2) + 4 * hi;
    xv_s[c * 72 + nn] = f2bf(acc[r] + bv[c]);
  }
  __syncthreads();
#pragma unroll
  for (int p = 0; p < 2; ++p) {
    int gid = t + p * 512;
    int c = gid & 127, ng = gid >> 7;
    s16x8 v = *(const s16x8*)(xv_s + c * 72 + ng * 8);
    size_t idx = (((size_t)b * 256 + (n0 >> 4) + (ng >> 1)) * 128 + c) * 16 + (ng & 1) * 8;
    *(s16x8*)(vfrag + idx) = v;
  }
}

// ============================================================================
// Flash attention, producer/consumer wave specialization.
// grid 256 = b(4) x it(64 tiles of 64 i). 512 thr = 8 waves = 4 pairs:
// even wave = SM (QK + exp2 + pack -> pa ring), odd wave = PV (ds_read pa +
// 16 MFMA). 2-slot ring, one __syncthreads per phase, 33 phases.
// ============================================================================
__global__ __launch_bounds__(512, 2) void attn_mfma(
    const short* __restrict__ qws, const short* __restrict__ kws, const short* __restrict__ vfrag,
    const float* __restrict__ x, const float* __restrict__ gp, float* __restrict__ out) {
  __shared__ __align__(16) unsigned char lds[68864];
  // pa ring @0 (32 KB); merge overlay: rg0 @0, rg1 @33792; lsc @67584; linv @68608

  int g = blockIdx.x;
  int gg = (g & 7) * 32 + (g >> 3);
  int b = gg >> 6;
  int it = gg & 63;
  int t = threadIdx.x;
  int w = t >> 6, lane = t & 63, lc = lane & 31, hi = lane >> 5;
  int pair = w >> 1, role = w & 1;
  int jt0 = pair * 1024;

  const short* qb = qws + (size_t)b * NT * 16;
  const short* kb = kws + (size_t)b * NT * 16;
  const short* vfb = vfrag + (size_t)b * 256 * 128 * 16;

  unsigned char* ring = lds + pair * 8192;

  f32x16 zf = {0.f,0.f,0.f,0.f,0.f,0.f,0.f,0.f,0.f,0.f,0.f,0.f,0.f,0.f,0.f,0.f};
  f32x16 acc[2][4];
#pragma unroll
  for (int i = 0; i < 2; ++i)
#pragma unroll
    for (int j = 0; j < 4; ++j) acc[i][j] = zf;
  float lsum0 = 0.f, lsum1 = 0.f;

  if (role == 0) {
    // ---------------- SM (producer) ----------------
    s16x8 qf0 = *(const s16x8*)(qb + (size_t)(it * 64 + lc) * 16 + hi * 8);
    s16x8 qf1 = *(const s16x8*)(qb + (size_t)(it * 64 + 32 + lc) * 16 + hi * 8);
    s16x8 kfC = *(const s16x8*)(kb + (size_t)(jt0 + lc) * 16 + hi * 8);
    for (int st = 0; st < 32; ++st) {
      s16x8 kfN = kfC;
      if (st < 31)
        kfN = *(const s16x8*)(kb + (size_t)(jt0 + (st + 1) * 32 + lc) * 16 + hi * 8);

      f32x16 e0 = __builtin_amdgcn_mfma_f32_32x32x16_bf16(kfC, qf0, zf, 0, 0, 0);
      f32x16 e1 = __builtin_amdgcn_mfma_f32_32x32x16_bf16(kfC, qf1, zf, 0, 0, 0);
#pragma unroll
      for (int r = 0; r < 16; ++r) e0[r] = __builtin_amdgcn_exp2f(e0[r]);
#pragma unroll
      for (int r = 0; r < 16; ++r) e1[r] = __builtin_amdgcn_exp2f(e1[r]);
      float a0 = 0.f, a1 = 0.f;
#pragma unroll
      for (int r = 0; r < 16; ++r) { a0 += e0[r]; a1 += e1[r]; }
      lsum0 += a0; lsum1 += a1;

      s16x8 pa0[2], pa1[2];
      pack_pa((const float*)&e0, pa0);
      pack_pa((const float*)&e1, pa1);

      unsigned char* slot = ring + (st & 1) * 4096 + lane * 16;
      *(s16x8*)(slot)        = pa0[0];
      *(s16x8*)(slot + 1024) = pa0[1];
      *(s16x8*)(slot + 2048) = pa1[0];
      *(s16x8*)(slot + 3072) = pa1[1];
      kfC = kfN;
      __syncthreads();                       // phases 0..31
    }
    __syncthreads();                         // phase 32
  } else {
    // ---------------- PV (consumer) ----------------
    s16x8 vA[2][4], vB[2][4];
#pragma unroll
    for (int sl = 0; sl < 2; ++sl)
#pragma unroll
      for (int cb = 0; cb < 4; ++cb)
        vA[sl][cb] = *(const s16x8*)(vfb + ((size_t)((jt0 >> 4) + sl) * 128 + cb * 32 + lc) * 16 + hi * 8);
    __syncthreads();                         // phase 0

    for (int kk = 0; kk < 16; ++kk) {
      int st = 2 * kk;
      if (st + 1 < 32) {
        int jtb = (jt0 >> 4) + (st + 1) * 2;
#pragma unroll
        for (int sl = 0; sl < 2; ++sl)
#pragma unroll
          for (int cb = 0; cb < 4; ++cb)
            vB[sl][cb] = *(const s16x8*)(vfb + ((size_t)(jtb + sl) * 128 + cb * 32 + lc) * 16 + hi * 8);
      }
      {
        const unsigned char* slot = ring + lane * 16;
        s16x8 pa0[2], pa1[2];
        pa0[0] = *(const s16x8*)(slot);
        pa0[1] = *(const s16x8*)(slot + 1024);
        pa1[0] = *(const s16x8*)(slot + 2048);
        pa1[1] = *(const s16x8*)(slot + 3072);
#pragma unroll
        for (int sl = 0; sl < 2; ++sl)
#pragma unroll
          for (int cb = 0; cb < 4; ++cb) {
            acc[0][cb] = __builtin_amdgcn_mfma_f32_32x32x16_bf16(pa0[sl], vA[sl][cb], acc[0][cb], 0, 0, 0);
            acc[1][cb] = __builtin_amdgcn_mfma_f32_32x32x16_bf16(pa1[sl], vA[sl][cb], acc[1][cb], 0, 0, 0);
          }
      }
      __syncthreads();                       // phase st+1

      if (st + 2 < 32) {
        int jtb = (jt0 >> 4) + (st + 2) * 2;
#pragma unroll
        for (int sl = 0; sl < 2; ++sl)
#pragma unroll
          for (int cb = 0; cb < 4; ++cb)
            vA[sl][cb] = *(const s16x8*)(vfb + ((size_t)(jtb + sl) * 128 + cb * 32 + lc) * 16 + hi * 8);
      }
      {
        const unsigned char* slot = ring + 4096 + lane * 16;
        s16x8 pa0[2], pa1[2];
        pa0[0] = *(const s16x8*)(slot);
        pa0[1] = *(const s16x8*)(slot + 1024);
        pa1[0] = *(const s16x8*)(slot + 2048);
        pa1[1] = *(const s16x8*)(slot + 3072);
#pragma unroll
        for (int sl = 0; sl < 2; ++sl)
#pragma unroll
          for (int cb = 0; cb < 4; ++cb) {
            acc[0][cb] = __builtin_amdgcn_mfma_f32_32x32x16_bf16(pa0[sl], vB[sl][cb], acc[0][cb], 0, 0, 0);
            acc[1][cb] = __builtin_amdgcn_mfma_f32_32x32x16_bf16(pa1[sl], vB[sl][cb], acc[1][cb], 0, 0, 0);
          }
      }
      __syncthreads();                       // phase st+2
    }
  }

  // ---- rejoin: L + acc merge (PV waves 1,3,5,7 hold pair partials) ----
  float* rg0  = (float*)lds;
  float* rg1  = (float*)(lds + 33792);
  float* lsc  = (float*)(lds + 67584);
  float* linv = (float*)(lds + 68608);

  float lf0 = lsum0 + __shfl_xor(lsum0, 32);
  float lf1 = lsum1 + __shfl_xor(lsum1, 32);
  if (role == 0 && hi == 0) { lsc[pair * 64 + lc] = lf0; lsc[pair * 64 + 32 + lc] = lf1; }
  if (w == 3) merge_write(rg0, acc, lc, hi);           // pair1
  if (w == 7) merge_write(rg1, acc, lc, hi);           // pair3
  __syncthreads();                                     // M1
  if (t < 64) {
    float L = lsc[t] + lsc[64 + t] + lsc[128 + t] + lsc[192 + t];
    linv[t] = 1.0f / L;
  }
  if (w == 1) merge_add(rg0, acc, lc, hi);             // pair0+pair1
  if (w == 5) merge_add(rg1, acc, lc, hi);             // pair2+pair3
  __syncthreads();                                     // M2
  if (w == 5) merge_write(rg1, acc, lc, hi);           // rg1 = {2,3}
  __syncthreads();                                     // M3
  if (w == 1) { merge_add(rg1, acc, lc, hi); merge_write(rg0, acc, lc, hi); }
  __syncthreads();                                     // M4

  // ---- epilogue: o = gamma * D/L + x ----
  float gam = gp[0];
  int cc = t >> 2, iq = t & 3;
  const float* xb = x + ((size_t)b * 128 + cc) * NT + it * 64 + iq * 16;
  float* ob = out + ((size_t)b * 128 + cc) * NT + it * 64 + iq * 16;
#pragma unroll
  for (int q2 = 0; q2 < 4; ++q2) {
    f32x4 xv = *(const f32x4*)(xb + q2 * 4);
    f32x4 ov;
#pragma unroll
    for (int j = 0; j < 4; ++j) {
      int i = iq * 16 + q2 * 4 + j;
      ov[j] = gam * rg0[i * 132 + cc] * linv[i] + xv[j];
    }
    *(f32x4*)(ob + q2 * 4) = ov;
  }
}

extern "C" void kernel_launch(void* const* d_in, const int* in_sizes, int n_in,
                              void* d_out, int out_size, void* d_ws, size_t ws_size,
                              hipStream_t stream) {
  const float* x     = (const float*)d_in[0];
  const float* wq    = (const float*)d_in[1];
  const float* bq    = (const float*)d_in[2];
  const float* wk    = (const float*)d_in[3];
  const float* bk    = (const float*)d_in[4];
  const float* wv    = (const float*)d_in[5];
  const float* bv    = (const float*)d_in[6];
  const float* gamma = (const float*)d_in[7];
  float* out = (float*)d_out;

  short* qws   = (short*)d_ws;                       // 512 KB
  short* kws   = qws + (size_t)4 * NT * 16;          // 512 KB
  short* vfrag = kws + (size_t)4 * NT * 16;          // 4 MB

  proj_kern<<<256, 512, 0, stream>>>(x, wq, bq, wk, bk, wv, bv, qws, kws, vfrag);
  attn_mfma<<<256, 512, 0, stream>>>(qws, kws, vfrag, x, gamma, out);
}